// Round 5
// baseline (369.092 us; speedup 1.0000x reference)
//
#include <hip/hip_runtime.h>

#define NN 8192
#define HD 512
#define NL 3
#define CAP 128
#define LN_EPS 1e-5f

typedef _Float16 f16;
typedef _Float16 f16x8 __attribute__((ext_vector_type(8)));
typedef _Float16 f16x4 __attribute__((ext_vector_type(4)));
typedef _Float16 f16x2 __attribute__((ext_vector_type(2)));
typedef float f32x4 __attribute__((ext_vector_type(4)));

__device__ __forceinline__ unsigned short f16_bits(f16 h) {
  union { f16 h; unsigned short u; } x; x.h = h; return x.u;
}
__device__ __forceinline__ f16 bits_f16(unsigned short u) {
  union { unsigned short u; f16 h; } x; x.u = u; return x.h;
}

__device__ __forceinline__ float dot2acc(f16x2 a, f16x2 b, float c) {
#if __has_builtin(__builtin_amdgcn_fdot2)
  return __builtin_amdgcn_fdot2(a, b, c, false);
#else
  return fmaf((float)a[0], (float)b[0], fmaf((float)a[1], (float)b[1], c));
#endif
}

// ---------------------------------------------------------------------------
// k_prep: one HBM pass over dense A (f32, symmetric, zero diag, entries >=0).
// Row staged in LDS, wave-scan ELL compaction: packed u32 = (f16(w)<<16)|col,
// self-loop w=1 appended (diag always 0), padded with w=0 to a multiple of 8.
// deg = rowsum + 1 -> dinv = deg^-1/2.  FUSED: also writes xs[r] = x0[r]*dinv[r]
// as f16 (removes the separate k_scalex dispatch).
__global__ __launch_bounds__(256) void k_prep(const float* __restrict__ A,
                                              const float* __restrict__ x0,
                                              unsigned* __restrict__ ell,
                                              int* __restrict__ nnz8,
                                              float* __restrict__ dinv,
                                              f16* __restrict__ xs) {
  __shared__ float rowbuf[NN];     // 32 KB staged row
  __shared__ int wtot[4];
  __shared__ float wsum[4];
  __shared__ float sdinv;
  const int r = blockIdx.x;
  const int t = threadIdx.x;
  const int lane = t & 63;
  const int wv = t >> 6;
  const float4* ar = (const float4*)(A + (size_t)r * NN);
  unsigned* er = ell + (size_t)r * CAP;

  int c = 0;
  float s = 0.f;
  for (int i = t; i < NN / 4; i += 256) {
    float4 v = ar[i];
    ((float4*)rowbuf)[i] = v;
    c += (v.x > 0.f) + (v.y > 0.f) + (v.z > 0.f) + (v.w > 0.f);
    s += v.x + v.y + v.z + v.w;   // entries are >= 0
  }
  int inc = c;
  #pragma unroll
  for (int d = 1; d < 64; d <<= 1) {
    int v = __shfl_up(inc, d);
    if (lane >= d) inc += v;
  }
  float ss = s;
  #pragma unroll
  for (int m = 1; m < 64; m <<= 1) ss += __shfl_xor(ss, m);
  if (lane == 63) wtot[wv] = inc;
  if (lane == 0) wsum[wv] = ss;
  __syncthreads();
  int base = inc - c;                       // exclusive within wave
  for (int w = 0; w < wv; w++) base += wtot[w];

  int o = base;
  for (int i = t; i < NN / 4; i += 256) {
    float4 v = ((float4*)rowbuf)[i];
    float vals[4] = {v.x, v.y, v.z, v.w};
    #pragma unroll
    for (int q = 0; q < 4; q++) {
      float val = vals[q];
      if (val > 0.f) {
        if (o < CAP) er[o] = ((unsigned)f16_bits((f16)val) << 16) | (unsigned)(i * 4 + q);
        o++;
      }
    }
  }
  if (t == 255) {
    int ne = wtot[0] + wtot[1] + wtot[2] + wtot[3];
    if (ne < CAP) er[ne] = (0x3C00u << 16) | (unsigned)r;   // self-loop w=1.0
    int ne1 = ne + 1; if (ne1 > CAP) ne1 = CAP;
    int n8 = (ne1 + 7) & ~7;
    for (int k = ne1; k < n8; k++) er[k] = (unsigned)r;     // w = +0.0 pad
    nnz8[r] = n8;
    float deg = wsum[0] + wsum[1] + wsum[2] + wsum[3] + 1.f;
    float di = rsqrtf(deg);
    dinv[r] = di;
    sdinv = di;
  }
  __syncthreads();
  // fused x-scale for row r: 512 f32 -> f16, 2 per thread
  {
    const float di = sdinv;
    const float2 xv = ((const float2*)(x0 + (size_t)r * HD))[t];
    f16x2 o2 = {(f16)(xv.x * di), (f16)(xv.y * di)};
    ((f16x2*)(xs + (size_t)r * HD))[t] = o2;
  }
}

// ---------------------------------------------------------------------------
// Column-chunked SpMM: y[r] = dinv[r] * sum_e w_e * xs[col_e].
// bid = chunk*2048 + rowblock; 4 waves/block, one row each; chunk = 128 cols
// (working set 2 MB, L2-resident per XCD).  Edges loaded as uniform uint4
// (s_load_dwordx4); per edge per lane: one f16x2 gather + one v_dot2_f32_f16.
__global__ __launch_bounds__(256) void k_spmm(const unsigned* __restrict__ ell,
                                              const int* __restrict__ nnz8,
                                              const float* __restrict__ dinv,
                                              const f16* __restrict__ xs,
                                              f16* __restrict__ y) {
  const int bid = blockIdx.x;              // 0..8191
  const int chunk = bid >> 11;             // 0..3
  const int rb = bid & 2047;
  const int r = __builtin_amdgcn_readfirstlane(rb * 4 + (threadIdx.x >> 6));
  const int lane = threadIdx.x & 63;
  const int c0 = chunk * 128 + lane * 2;
  const uint4* er = (const uint4*)(ell + (size_t)r * CAP);
  const int ne = nnz8[r];
  const f16* xc = xs + c0;
  float acc = 0.f;
  for (int e8 = 0; e8 < (ne >> 3); e8++) {
    const uint4 ea = er[e8 * 2];
    const uint4 eb = er[e8 * 2 + 1];
    unsigned wv[8] = {ea.x, ea.y, ea.z, ea.w, eb.x, eb.y, eb.z, eb.w};
    f16x2 xv[8];
    #pragma unroll
    for (int q = 0; q < 8; q++)
      xv[q] = *(const f16x2*)(xc + (size_t)(wv[q] & 0xFFFFu) * HD);
    #pragma unroll
    for (int q = 0; q < 8; q++) {
      const f16 fw = bits_f16((unsigned short)(wv[q] >> 16));
      f16x2 wp = {fw, fw};
      acc = dot2acc(xv[q], wp, acc);
    }
  }
  const float s = dinv[r];
  // note: fdot2 sums both halves; we need per-column results -> redo as pair
  // (kept separate accumulators below instead)
  (void)acc;
  // --- actual per-column accumulation (two scalars) ---
  float a0 = 0.f, a1 = 0.f;
  for (int e8 = 0; e8 < (ne >> 3); e8++) {
    const uint4 ea = er[e8 * 2];
    const uint4 eb = er[e8 * 2 + 1];
    unsigned wv[8] = {ea.x, ea.y, ea.z, ea.w, eb.x, eb.y, eb.z, eb.w};
    f16x2 xv[8];
    #pragma unroll
    for (int q = 0; q < 8; q++)
      xv[q] = *(const f16x2*)(xc + (size_t)(wv[q] & 0xFFFFu) * HD);
    #pragma unroll
    for (int q = 0; q < 8; q++) {
      const float fw = (float)bits_f16((unsigned short)(wv[q] >> 16));
      a0 = fmaf(fw, (float)xv[q][0], a0);
      a1 = fmaf(fw, (float)xv[q][1], a1);
    }
  }
  f16x2 o = {(f16)(a0 * s), (f16)(a1 * s)};
  *(f16x2*)(y + (size_t)r * HD + c0) = o;
}

// ---------------------------------------------------------------------------
// Fused GEMM + bias + LayerNorm + ReLU + optional dinv scale, f16 out.
// M=32 x N=512 per block (256 blocks = full GPU), 512 threads = 8 waves in
// 2 rowgroups x 4 colgroups; wave = 16 rows x 128 cols = 1 a-frag x 8 b-frags.
// Per-CU W streaming = 512 KB (L1 floor ~3.4 us) -- unlike the failed M=16
// version which pulled 1 MB/CU.
__global__ __launch_bounds__(512) void k_gemm_ln(const f16* __restrict__ y,
                                                 const f16* __restrict__ WT,
                                                 const float* __restrict__ bias,
                                                 const float* __restrict__ g,
                                                 const float* __restrict__ bb,
                                                 const float* __restrict__ dscale,
                                                 f16* __restrict__ outp) {
  __shared__ float red[32][4][2];
  const int t = threadIdx.x;
  const int lane = t & 63;
  const int w = t >> 6;
  const int wm = w >> 2;          // 0..1 rowgroup
  const int wn = w & 3;           // 0..3 colgroup
  const int m0 = blockIdx.x * 32;
  const int rl = lane & 15, kg = (lane >> 4) * 8;
  const f16* aP = y + (size_t)(m0 + wm * 16 + rl) * HD + kg;
  const f16* bP = WT + (size_t)(wn * 128 + rl) * HD + kg;

  f32x4 acc[8];
  #pragma unroll
  for (int j = 0; j < 8; j++) { f32x4 z = {0.f, 0.f, 0.f, 0.f}; acc[j] = z; }

  #pragma unroll 2
  for (int ks = 0; ks < HD; ks += 32) {
    const f16x8 af = *(const f16x8*)(aP + ks);
    #pragma unroll
    for (int j = 0; j < 8; j++) {
      const f16x8 bf = *(const f16x8*)(bP + (size_t)j * 16 * HD + ks);
      acc[j] = __builtin_amdgcn_mfma_f32_16x16x32_f16(af, bf, acc[j], 0, 0, 0);
    }
  }

  const int cg = lane >> 4, cl = lane & 15;
  float av[8][4];
  #pragma unroll
  for (int j = 0; j < 8; j++) {
    const float bv = bias[wn * 128 + j * 16 + cl];
    #pragma unroll
    for (int r = 0; r < 4; r++) av[j][r] = acc[j][r] + bv;
  }
  #pragma unroll
  for (int r = 0; r < 4; r++) {
    float s = 0.f, sq = 0.f;
    #pragma unroll
    for (int j = 0; j < 8; j++) { s += av[j][r]; sq += av[j][r] * av[j][r]; }
    #pragma unroll
    for (int m = 1; m < 16; m <<= 1) { s += __shfl_xor(s, m); sq += __shfl_xor(sq, m); }
    if (cl == 0) {
      red[wm * 16 + cg * 4 + r][wn][0] = s;
      red[wm * 16 + cg * 4 + r][wn][1] = sq;
    }
  }
  __syncthreads();
  #pragma unroll
  for (int r = 0; r < 4; r++) {
    const int rb = wm * 16 + cg * 4 + r;
    float s = 0.f, sq = 0.f;
    #pragma unroll
    for (int q = 0; q < 4; q++) { s += red[rb][q][0]; sq += red[rb][q][1]; }
    const float mu = s * (1.f / HD);
    const float rs = rsqrtf(sq * (1.f / HD) - mu * mu + LN_EPS);
    const int row = m0 + rb;
    const float dsc = dscale ? dscale[row] : 1.f;
    #pragma unroll
    for (int j = 0; j < 8; j++) {
      const int col = wn * 128 + j * 16 + cl;
      const float val = fmaxf((av[j][r] - mu) * rs * g[col] + bb[col], 0.f) * dsc;
      outp[(size_t)row * HD + col] = (f16)val;
    }
  }
}

// ---------------------------------------------------------------------------
// Direct-from-L2 MFMA GEMM (final linear): C[M,512] = A[M,512] @ BT^T + bias.
__global__ __launch_bounds__(256) void k_gemm_direct(const f16* __restrict__ A,
                                                     const f16* __restrict__ BT,
                                                     float* __restrict__ C,
                                                     const float* __restrict__ bias) {
  const int t = threadIdx.x;
  const int lane = t & 63;
  const int wave = t >> 6;
  const int wm = wave >> 1, wn = wave & 1;
  const int m0 = blockIdx.x * 128, n0 = blockIdx.y * 128;
  const int rl = lane & 15, kg = (lane >> 4) * 8;

  const f16* aP[4];
  const f16* bP[4];
  #pragma unroll
  for (int i = 0; i < 4; i++)
    aP[i] = A + (size_t)(m0 + wm * 64 + i * 16 + rl) * HD + kg;
  #pragma unroll
  for (int j = 0; j < 4; j++)
    bP[j] = BT + (size_t)(n0 + wn * 64 + j * 16 + rl) * HD + kg;

  f32x4 acc[4][4];
  #pragma unroll
  for (int i = 0; i < 4; i++)
    #pragma unroll
    for (int j = 0; j < 4; j++) {
      f32x4 z = {0.f, 0.f, 0.f, 0.f};
      acc[i][j] = z;
    }

  #pragma unroll 4
  for (int ks = 0; ks < HD; ks += 32) {
    f16x8 af[4], bf[4];
    #pragma unroll
    for (int i = 0; i < 4; i++) af[i] = *(const f16x8*)(aP[i] + ks);
    #pragma unroll
    for (int j = 0; j < 4; j++) bf[j] = *(const f16x8*)(bP[j] + ks);
    #pragma unroll
    for (int i = 0; i < 4; i++)
      #pragma unroll
      for (int j = 0; j < 4; j++)
        acc[i][j] = __builtin_amdgcn_mfma_f32_16x16x32_f16(af[i], bf[j], acc[i][j], 0, 0, 0);
  }

  const int cg = lane >> 4, cl = lane & 15;
  #pragma unroll
  for (int i = 0; i < 4; i++) {
    #pragma unroll
    for (int j = 0; j < 4; j++) {
      const int col = n0 + wn * 64 + j * 16 + cl;
      const float bv = bias ? bias[col] : 0.f;
      #pragma unroll
      for (int rr = 0; rr < 4; rr++) {
        const int row = m0 + wm * 64 + i * 16 + cg * 4 + rr;
        C[(size_t)row * HD + col] = acc[i][j][rr] + bv;
      }
    }
  }
}

// ---------------------------------------------------------------------------
// WlT[n][m] = (Wc @ Wm)[m][n], f16.  2 m-rows/block, grid (256, NL):
// ~2048 FMA/thread, full-GPU parallel.
__global__ __launch_bounds__(256) void k_wcomb(const float* __restrict__ convw,
                                               const float* __restrict__ mlpw,
                                               f16* __restrict__ WlT) {
  const int l = blockIdx.y;
  const int m0 = blockIdx.x * 2;
  const float* Wc = convw + (size_t)l * HD * HD;
  const float* Wm = mlpw + (size_t)l * HD * HD;
  f16* o = WlT + (size_t)l * HD * HD;
  const int n = threadIdx.x;
  float a00 = 0.f, a01 = 0.f, a10 = 0.f, a11 = 0.f;
  const float* wc0 = Wc + (size_t)m0 * HD;
  const float* wc1 = Wc + (size_t)(m0 + 1) * HD;
  for (int k = 0; k < HD; k++) {
    const float w0 = Wm[(size_t)k * HD + n];
    const float w1 = Wm[(size_t)k * HD + n + 256];
    const float c0 = wc0[k];
    const float c1 = wc1[k];
    a00 = fmaf(c0, w0, a00);
    a01 = fmaf(c0, w1, a01);
    a10 = fmaf(c1, w0, a10);
    a11 = fmaf(c1, w1, a11);
  }
  o[(size_t)n * HD + m0] = (f16)a00;
  o[(size_t)(n + 256) * HD + m0] = (f16)a01;
  o[(size_t)n * HD + m0 + 1] = (f16)a10;
  o[(size_t)(n + 256) * HD + m0 + 1] = (f16)a11;
}

// bl[l][n] = conv_b[l] @ Wm[l] + mlp_b[l][n].
__global__ void k_bcomb(const float* __restrict__ convb, const float* __restrict__ mlpw,
                        const float* __restrict__ mlpb, float* __restrict__ bl) {
  const int l = blockIdx.x;
  const int n = threadIdx.x;
  const float* Wm = mlpw + (size_t)l * HD * HD;
  float acc = mlpb[l * HD + n];
  for (int k = 0; k < HD; k++) acc = fmaf(convb[l * HD + k], Wm[(size_t)k * HD + n], acc);
  bl[l * HD + n] = acc;
}

// lwT[n][k] = lin_w[k][n], f32 -> f16.
__global__ __launch_bounds__(256) void k_twl(const float* __restrict__ lw,
                                             f16* __restrict__ lwT) {
  const int k = blockIdx.x;
  for (int n = threadIdx.x; n < HD; n += 256)
    lwT[(size_t)n * HD + k] = (f16)lw[(size_t)k * HD + n];
}

// ---------------------------------------------------------------------------
extern "C" void kernel_launch(void* const* d_in, const int* in_sizes, int n_in,
                              void* d_out, int out_size, void* d_ws, size_t ws_size,
                              hipStream_t stream) {
  const float* node_feat = (const float*)d_in[0];
  const float* adj       = (const float*)d_in[1];
  const float* conv_w    = (const float*)d_in[2];
  const float* conv_b    = (const float*)d_in[3];
  const float* mlp_w     = (const float*)d_in[4];
  const float* mlp_b     = (const float*)d_in[5];
  const float* ln_g      = (const float*)d_in[6];
  const float* ln_b      = (const float*)d_in[7];
  const float* lin_w     = (const float*)d_in[8];
  const float* lin_b     = (const float*)d_in[9];
  float* out = (float*)d_out;

  // workspace carve (~29 MB)
  char* p = (char*)d_ws;
  unsigned* ell = (unsigned*)p; p += (size_t)NN * CAP * 4;   // 4 MB
  int* nnz8  = (int*)p;   p += (size_t)NN * 4;
  float* dinv = (float*)p; p += (size_t)NN * 4;
  f16* xsA   = (f16*)p;   p += (size_t)NN * HD * 2;          // 8 MB
  f16* xsB   = (f16*)p;   p += (size_t)NN * HD * 2;          // 8 MB
  f16* ybuf  = (f16*)p;   p += (size_t)NN * HD * 2;          // 8 MB
  f16* WlT   = (f16*)p;   p += (size_t)NL * HD * HD * 2;
  f16* lwT   = (f16*)p;   p += (size_t)HD * HD * 2;
  float* bl  = (float*)p; p += (size_t)NL * HD * 4;

  k_prep<<<NN, 256, 0, stream>>>(adj, node_feat, ell, nnz8, dinv, xsA);
  k_wcomb<<<dim3(256, NL), 256, 0, stream>>>(conv_w, mlp_w, WlT);
  k_bcomb<<<NL, HD, 0, stream>>>(conv_b, mlp_w, mlp_b, bl);
  k_twl<<<HD, 256, 0, stream>>>(lin_w, lwT);

  f16* xcur = xsA;
  for (int l = 0; l < NL; l++) {
    k_spmm<<<NN, 256, 0, stream>>>(ell, nnz8, dinv, xcur, ybuf);
    f16* nxt = (xcur == xsA) ? xsB : xsA;
    k_gemm_ln<<<NN / 32, 512, 0, stream>>>(ybuf, WlT + (size_t)l * HD * HD,
                                           bl + l * HD, ln_g + l * HD, ln_b + l * HD,
                                           (l < 2) ? dinv : nullptr, nxt);
    xcur = nxt;
  }
  k_gemm_direct<<<dim3(64, 4), 256, 0, stream>>>(xcur, lwT, out, lin_b);
}

// Round 6
// 337.587 us; speedup vs baseline: 1.0933x; 1.0933x over previous
//
#include <hip/hip_runtime.h>

#define NN 8192
#define HD 512
#define NL 3
#define CAP 128
#define LN_EPS 1e-5f

typedef _Float16 f16;
typedef _Float16 f16x8 __attribute__((ext_vector_type(8)));
typedef _Float16 f16x4 __attribute__((ext_vector_type(4)));
typedef _Float16 f16x2 __attribute__((ext_vector_type(2)));
typedef float f32x4 __attribute__((ext_vector_type(4)));

__device__ __forceinline__ unsigned short f16_bits(f16 h) {
  union { f16 h; unsigned short u; } x; x.h = h; return x.u;
}
__device__ __forceinline__ f16 bits_f16(unsigned short u) {
  union { unsigned short u; f16 h; } x; x.u = u; return x.h;
}

// ---------------------------------------------------------------------------
// k_prep: one HBM pass over dense A (f32, symmetric, zero diag, entries >=0).
// Row staged in REGISTERS (8 float4/thread = 32 VGPR) -- no 32KB LDS buffer,
// so occupancy is 8 blocks/CU and the read pipe stays saturated through the
// scan/emit phases.  Emits ELL: packed u32 = (f16(w)<<16)|col, self-loop w=1
// appended (diag always 0), padded with w=0 to a multiple of 8.
// deg = rowsum+1 -> dinv = deg^-1/2.  Fused: xs[r] = x0[r]*dinv[r] (f16).
__global__ __launch_bounds__(256) void k_prep(const float* __restrict__ A,
                                              const float* __restrict__ x0,
                                              unsigned* __restrict__ ell,
                                              int* __restrict__ nnz8,
                                              float* __restrict__ dinv,
                                              f16* __restrict__ xs) {
  __shared__ int wtot[4];
  __shared__ float wsum[4];
  __shared__ float sdinv;
  const int r = blockIdx.x;
  const int t = threadIdx.x;
  const int lane = t & 63;
  const int wv = t >> 6;
  const float4* ar = (const float4*)(A + (size_t)r * NN);
  unsigned* er = ell + (size_t)r * CAP;

  float4 v[8];
  int c = 0;
  float s = 0.f;
  #pragma unroll
  for (int i = 0; i < 8; i++) {
    v[i] = ar[t + i * 256];
    c += (v[i].x > 0.f) + (v[i].y > 0.f) + (v[i].z > 0.f) + (v[i].w > 0.f);
    s += v[i].x + v[i].y + v[i].z + v[i].w;   // entries are >= 0
  }
  int inc = c;
  #pragma unroll
  for (int d = 1; d < 64; d <<= 1) {
    int vv = __shfl_up(inc, d);
    if (lane >= d) inc += vv;
  }
  float ss = s;
  #pragma unroll
  for (int m = 1; m < 64; m <<= 1) ss += __shfl_xor(ss, m);
  if (lane == 63) wtot[wv] = inc;
  if (lane == 0) wsum[wv] = ss;
  __syncthreads();
  int base = inc - c;                       // exclusive within wave
  for (int w = 0; w < wv; w++) base += wtot[w];

  int o = base;
  #pragma unroll
  for (int i = 0; i < 8; i++) {
    float vals[4] = {v[i].x, v[i].y, v[i].z, v[i].w};
    #pragma unroll
    for (int q = 0; q < 4; q++) {
      float val = vals[q];
      if (val > 0.f) {
        if (o < CAP) er[o] = ((unsigned)f16_bits((f16)val) << 16) | (unsigned)((t + i * 256) * 4 + q);
        o++;
      }
    }
  }
  if (t == 255) {
    int ne = wtot[0] + wtot[1] + wtot[2] + wtot[3];
    if (ne < CAP) er[ne] = (0x3C00u << 16) | (unsigned)r;   // self-loop w=1.0
    int ne1 = ne + 1; if (ne1 > CAP) ne1 = CAP;
    int n8 = (ne1 + 7) & ~7;
    for (int k = ne1; k < n8; k++) er[k] = (unsigned)r;     // w = +0.0 pad
    nnz8[r] = n8;
    float deg = wsum[0] + wsum[1] + wsum[2] + wsum[3] + 1.f;
    float di = rsqrtf(deg);
    dinv[r] = di;
    sdinv = di;
  }
  __syncthreads();
  // fused x-scale for row r: 512 f32 -> f16, 2 per thread
  {
    const float di = sdinv;
    const float2 xv = ((const float2*)(x0 + (size_t)r * HD))[t];
    f16x2 o2 = {(f16)(xv.x * di), (f16)(xv.y * di)};
    ((f16x2*)(xs + (size_t)r * HD))[t] = o2;
  }
}

// ---------------------------------------------------------------------------
// Column-chunked SpMM: y[r] = dinv[r] * sum_e w_e * xs[col_e].
// bid = chunk*2048 + rowblock; 4 waves/block, one row each; chunk = 128 cols
// (working set 2 MB, L2-resident per XCD).  Edges via uniform uint4 s_loads;
// per edge per lane: one f16x2 gather + 2 fma.
__global__ __launch_bounds__(256) void k_spmm(const unsigned* __restrict__ ell,
                                              const int* __restrict__ nnz8,
                                              const float* __restrict__ dinv,
                                              const f16* __restrict__ xs,
                                              f16* __restrict__ y) {
  const int bid = blockIdx.x;              // 0..8191
  const int chunk = bid >> 11;             // 0..3
  const int rb = bid & 2047;
  const int r = __builtin_amdgcn_readfirstlane(rb * 4 + (threadIdx.x >> 6));
  const int lane = threadIdx.x & 63;
  const int c0 = chunk * 128 + lane * 2;
  const uint4* er = (const uint4*)(ell + (size_t)r * CAP);
  const int ne = nnz8[r];
  const f16* xc = xs + c0;
  float a0 = 0.f, a1 = 0.f;
  for (int e8 = 0; e8 < (ne >> 3); e8++) {
    const uint4 ea = er[e8 * 2];
    const uint4 eb = er[e8 * 2 + 1];
    unsigned wv[8] = {ea.x, ea.y, ea.z, ea.w, eb.x, eb.y, eb.z, eb.w};
    f16x2 xv[8];
    #pragma unroll
    for (int q = 0; q < 8; q++)
      xv[q] = *(const f16x2*)(xc + (size_t)(wv[q] & 0xFFFFu) * HD);
    #pragma unroll
    for (int q = 0; q < 8; q++) {
      const float fw = (float)bits_f16((unsigned short)(wv[q] >> 16));
      a0 = fmaf(fw, (float)xv[q][0], a0);
      a1 = fmaf(fw, (float)xv[q][1], a1);
    }
  }
  const float s = dinv[r];
  f16x2 o = {(f16)(a0 * s), (f16)(a1 * s)};
  *(f16x2*)(y + (size_t)r * HD + c0) = o;
}

// ---------------------------------------------------------------------------
// Fused GEMM + bias + LayerNorm + ReLU + optional dinv scale, f16 out.
// M=32 x N=512 per block (256 blocks = full GPU), 512 threads = 8 waves in
// 2 rowgroups x 4 colgroups; per-CU W streaming = 512 KB.
__global__ __launch_bounds__(512) void k_gemm_ln(const f16* __restrict__ y,
                                                 const f16* __restrict__ WT,
                                                 const float* __restrict__ bias,
                                                 const float* __restrict__ g,
                                                 const float* __restrict__ bb,
                                                 const float* __restrict__ dscale,
                                                 f16* __restrict__ outp) {
  __shared__ float red[32][4][2];
  const int t = threadIdx.x;
  const int lane = t & 63;
  const int w = t >> 6;
  const int wm = w >> 2;          // 0..1 rowgroup
  const int wn = w & 3;           // 0..3 colgroup
  const int m0 = blockIdx.x * 32;
  const int rl = lane & 15, kg = (lane >> 4) * 8;
  const f16* aP = y + (size_t)(m0 + wm * 16 + rl) * HD + kg;
  const f16* bP = WT + (size_t)(wn * 128 + rl) * HD + kg;

  f32x4 acc[8];
  #pragma unroll
  for (int j = 0; j < 8; j++) { f32x4 z = {0.f, 0.f, 0.f, 0.f}; acc[j] = z; }

  #pragma unroll 2
  for (int ks = 0; ks < HD; ks += 32) {
    const f16x8 af = *(const f16x8*)(aP + ks);
    #pragma unroll
    for (int j = 0; j < 8; j++) {
      const f16x8 bf = *(const f16x8*)(bP + (size_t)j * 16 * HD + ks);
      acc[j] = __builtin_amdgcn_mfma_f32_16x16x32_f16(af, bf, acc[j], 0, 0, 0);
    }
  }

  const int cg = lane >> 4, cl = lane & 15;
  float av[8][4];
  #pragma unroll
  for (int j = 0; j < 8; j++) {
    const float bv = bias[wn * 128 + j * 16 + cl];
    #pragma unroll
    for (int r = 0; r < 4; r++) av[j][r] = acc[j][r] + bv;
  }
  #pragma unroll
  for (int r = 0; r < 4; r++) {
    float s = 0.f, sq = 0.f;
    #pragma unroll
    for (int j = 0; j < 8; j++) { s += av[j][r]; sq += av[j][r] * av[j][r]; }
    #pragma unroll
    for (int m = 1; m < 16; m <<= 1) { s += __shfl_xor(s, m); sq += __shfl_xor(sq, m); }
    if (cl == 0) {
      red[wm * 16 + cg * 4 + r][wn][0] = s;
      red[wm * 16 + cg * 4 + r][wn][1] = sq;
    }
  }
  __syncthreads();
  #pragma unroll
  for (int r = 0; r < 4; r++) {
    const int rb = wm * 16 + cg * 4 + r;
    float s = 0.f, sq = 0.f;
    #pragma unroll
    for (int q = 0; q < 4; q++) { s += red[rb][q][0]; sq += red[rb][q][1]; }
    const float mu = s * (1.f / HD);
    const float rs = rsqrtf(sq * (1.f / HD) - mu * mu + LN_EPS);
    const int row = m0 + rb;
    const float dsc = dscale ? dscale[row] : 1.f;
    #pragma unroll
    for (int j = 0; j < 8; j++) {
      const int col = wn * 128 + j * 16 + cl;
      const float val = fmaxf((av[j][r] - mu) * rs * g[col] + bb[col], 0.f) * dsc;
      outp[(size_t)row * HD + col] = (f16)val;
    }
  }
}

// ---------------------------------------------------------------------------
// Direct-from-L2 MFMA GEMM (final linear): C[M,512] = A[M,512] @ BT^T + bias.
__global__ __launch_bounds__(256) void k_gemm_direct(const f16* __restrict__ A,
                                                     const f16* __restrict__ BT,
                                                     float* __restrict__ C,
                                                     const float* __restrict__ bias) {
  const int t = threadIdx.x;
  const int lane = t & 63;
  const int wave = t >> 6;
  const int wm = wave >> 1, wn = wave & 1;
  const int m0 = blockIdx.x * 128, n0 = blockIdx.y * 128;
  const int rl = lane & 15, kg = (lane >> 4) * 8;

  const f16* aP[4];
  const f16* bP[4];
  #pragma unroll
  for (int i = 0; i < 4; i++)
    aP[i] = A + (size_t)(m0 + wm * 64 + i * 16 + rl) * HD + kg;
  #pragma unroll
  for (int j = 0; j < 4; j++)
    bP[j] = BT + (size_t)(n0 + wn * 64 + j * 16 + rl) * HD + kg;

  f32x4 acc[4][4];
  #pragma unroll
  for (int i = 0; i < 4; i++)
    #pragma unroll
    for (int j = 0; j < 4; j++) {
      f32x4 z = {0.f, 0.f, 0.f, 0.f};
      acc[i][j] = z;
    }

  #pragma unroll 4
  for (int ks = 0; ks < HD; ks += 32) {
    f16x8 af[4], bf[4];
    #pragma unroll
    for (int i = 0; i < 4; i++) af[i] = *(const f16x8*)(aP[i] + ks);
    #pragma unroll
    for (int j = 0; j < 4; j++) bf[j] = *(const f16x8*)(bP[j] + ks);
    #pragma unroll
    for (int i = 0; i < 4; i++)
      #pragma unroll
      for (int j = 0; j < 4; j++)
        acc[i][j] = __builtin_amdgcn_mfma_f32_16x16x32_f16(af[i], bf[j], acc[i][j], 0, 0, 0);
  }

  const int cg = lane >> 4, cl = lane & 15;
  #pragma unroll
  for (int i = 0; i < 4; i++) {
    #pragma unroll
    for (int j = 0; j < 4; j++) {
      const int col = n0 + wn * 64 + j * 16 + cl;
      const float bv = bias ? bias[col] : 0.f;
      #pragma unroll
      for (int rr = 0; rr < 4; rr++) {
        const int row = m0 + wm * 64 + i * 16 + cg * 4 + rr;
        C[(size_t)row * HD + col] = acc[i][j][rr] + bv;
      }
    }
  }
}

// ---------------------------------------------------------------------------
// One dispatch for all weight prep.  grid (273, NL), 256 threads.
//  bx < 256 : WlT[n][m] = (Wc@Wm)[m][n] f16, 2 m-rows per block
//  bx == 256: bl[l][n] = conv_b[l]@Wm[l] + mlp_b[l][n]
//  bx > 256 : (l==0 only) lwT[n][k] = lin_w[k][n] f16, 16 blocks
__global__ __launch_bounds__(256) void k_weights(const float* __restrict__ convw,
                                                 const float* __restrict__ mlpw,
                                                 const float* __restrict__ convb,
                                                 const float* __restrict__ mlpb,
                                                 const float* __restrict__ lw,
                                                 f16* __restrict__ WlT,
                                                 float* __restrict__ bl,
                                                 f16* __restrict__ lwT) {
  const int l = blockIdx.y;
  const int bx = blockIdx.x;
  const int t = threadIdx.x;
  if (bx < 256) {
    const int m0 = bx * 2;
    const float* Wc = convw + (size_t)l * HD * HD;
    const float* Wm = mlpw + (size_t)l * HD * HD;
    f16* o = WlT + (size_t)l * HD * HD;
    float a00 = 0.f, a01 = 0.f, a10 = 0.f, a11 = 0.f;
    const float* wc0 = Wc + (size_t)m0 * HD;
    const float* wc1 = Wc + (size_t)(m0 + 1) * HD;
    for (int k = 0; k < HD; k++) {
      const float w0 = Wm[(size_t)k * HD + t];
      const float w1 = Wm[(size_t)k * HD + t + 256];
      const float c0 = wc0[k];
      const float c1 = wc1[k];
      a00 = fmaf(c0, w0, a00);
      a01 = fmaf(c0, w1, a01);
      a10 = fmaf(c1, w0, a10);
      a11 = fmaf(c1, w1, a11);
    }
    o[(size_t)t * HD + m0] = (f16)a00;
    o[(size_t)(t + 256) * HD + m0] = (f16)a01;
    o[(size_t)t * HD + m0 + 1] = (f16)a10;
    o[(size_t)(t + 256) * HD + m0 + 1] = (f16)a11;
  } else if (bx == 256) {
    const float* Wm = mlpw + (size_t)l * HD * HD;
    float acc0 = mlpb[l * HD + t];
    float acc1 = mlpb[l * HD + t + 256];
    for (int k = 0; k < HD; k++) {
      const float cb = convb[l * HD + k];
      acc0 = fmaf(cb, Wm[(size_t)k * HD + t], acc0);
      acc1 = fmaf(cb, Wm[(size_t)k * HD + t + 256], acc1);
    }
    bl[l * HD + t] = acc0;
    bl[l * HD + t + 256] = acc1;
  } else if (l == 0) {
    const int base = (bx - 257) * 16384;   // 16 blocks cover 512*512
    #pragma unroll 4
    for (int j = 0; j < 64; j++) {
      const int idx = base + j * 256 + t;
      const int k = idx >> 9, n = idx & 511;
      lwT[(size_t)n * HD + k] = (f16)lw[idx];
    }
  }
}

// ---------------------------------------------------------------------------
extern "C" void kernel_launch(void* const* d_in, const int* in_sizes, int n_in,
                              void* d_out, int out_size, void* d_ws, size_t ws_size,
                              hipStream_t stream) {
  const float* node_feat = (const float*)d_in[0];
  const float* adj       = (const float*)d_in[1];
  const float* conv_w    = (const float*)d_in[2];
  const float* conv_b    = (const float*)d_in[3];
  const float* mlp_w     = (const float*)d_in[4];
  const float* mlp_b     = (const float*)d_in[5];
  const float* ln_g      = (const float*)d_in[6];
  const float* ln_b      = (const float*)d_in[7];
  const float* lin_w     = (const float*)d_in[8];
  const float* lin_b     = (const float*)d_in[9];
  float* out = (float*)d_out;

  // workspace carve (~29 MB)
  char* p = (char*)d_ws;
  unsigned* ell = (unsigned*)p; p += (size_t)NN * CAP * 4;   // 4 MB
  int* nnz8  = (int*)p;   p += (size_t)NN * 4;
  float* dinv = (float*)p; p += (size_t)NN * 4;
  f16* xsA   = (f16*)p;   p += (size_t)NN * HD * 2;          // 8 MB
  f16* xsB   = (f16*)p;   p += (size_t)NN * HD * 2;          // 8 MB
  f16* ybuf  = (f16*)p;   p += (size_t)NN * HD * 2;          // 8 MB
  f16* WlT   = (f16*)p;   p += (size_t)NL * HD * HD * 2;
  f16* lwT   = (f16*)p;   p += (size_t)HD * HD * 2;
  float* bl  = (float*)p; p += (size_t)NL * HD * 4;

  k_prep<<<NN, 256, 0, stream>>>(adj, node_feat, ell, nnz8, dinv, xsA);
  k_weights<<<dim3(273, NL), 256, 0, stream>>>(conv_w, mlp_w, conv_b, mlp_b,
                                               lin_w, WlT, bl, lwT);

  f16* xcur = xsA;
  for (int l = 0; l < NL; l++) {
    k_spmm<<<NN, 256, 0, stream>>>(ell, nnz8, dinv, xcur, ybuf);
    f16* nxt = (xcur == xsA) ? xsB : xsA;
    k_gemm_ln<<<NN / 32, 512, 0, stream>>>(ybuf, WlT + (size_t)l * HD * HD,
                                           bl + l * HD, ln_g + l * HD, ln_b + l * HD,
                                           (l < 2) ? dinv : nullptr, nxt);
    xcur = nxt;
  }
  k_gemm_direct<<<dim3(64, 4), 256, 0, stream>>>(xcur, lwT, out, lin_b);
}